// Round 15
// baseline (207.532 us; speedup 1.0000x reference)
//
#include <hip/hip_runtime.h>
#include <hip/hip_fp16.h>
#include <cstdint>

#define T_STEPS 32
#define NB 64
#define STATE 64
#define HID 128
#define ACT 32
#define CDIM 96
#define G3 (3*HID)   // 384

typedef __attribute__((ext_vector_type(8))) short short8;
typedef __attribute__((ext_vector_type(4))) float f32x4;
typedef _Float16 h2v __attribute__((ext_vector_type(2)));

__device__ __forceinline__ unsigned short f2bf(float f){
  unsigned int u = __builtin_bit_cast(unsigned int, f);
  u = u + 0x7FFFu + ((u >> 16) & 1u);
  return (unsigned short)(u >> 16);
}
__device__ __forceinline__ float bf2f(unsigned short u){
  unsigned int v = ((unsigned int)u) << 16; return __builtin_bit_cast(float, v);
}
__device__ __forceinline__ unsigned int packh2(float f0, float f1){
  return (unsigned int)__half_as_ushort(__float2half_rn(f0)) |
         ((unsigned int)__half_as_ushort(__float2half_rn(f1)) << 16);
}
__device__ __forceinline__ float sigmoidf_(float x){ return 1.0f/(1.0f + __expf(-x)); }
__device__ __forceinline__ float tanhf_(float x){ float e = __expf(2.0f*x); return (e-1.0f)/(e+1.0f); }

__device__ __forceinline__ float dot2f(float acc, unsigned int a, unsigned int b){
  h2v av = __builtin_bit_cast(h2v, a);
  h2v bv = __builtin_bit_cast(h2v, b);
  return __builtin_amdgcn_fdot2(av, bv, acc, false);
}
__device__ __forceinline__ float l1d(float acc, unsigned int ua, unsigned int ub){
  __half2 a = __builtin_bit_cast(__half2, ua);
  __half2 b = __builtin_bit_cast(__half2, ub);
  __half2 d = __habs2(__hsub2(a, b));
  h2v dv = __builtin_bit_cast(h2v, d);
  h2v ones; ones[0] = (_Float16)1.0f; ones[1] = (_Float16)1.0f;
  return __builtin_amdgcn_fdot2(dv, ones, acc, false);
}
__device__ __forceinline__ float l1d4(float acc, uint4 a, uint4 b){
  acc = l1d(acc, a.x, b.x); acc = l1d(acc, a.y, b.y);
  acc = l1d(acc, a.z, b.z); acc = l1d(acc, a.w, b.w);
  return acc;
}

// ---------------- prep ----------------
__global__ void k_prep(const float* __restrict__ Tm, unsigned short* __restrict__ tmh,
                       const float* __restrict__ whh0, const float* __restrict__ whh1,
                       const float* __restrict__ w1, const float* __restrict__ wih0,
                       const float* __restrict__ wih1, const float* __restrict__ x,
                       const float* __restrict__ a,
                       unsigned int* __restrict__ whh0p, unsigned int* __restrict__ whh1p,
                       unsigned short* __restrict__ w1f, unsigned short* __restrict__ wi0f,
                       unsigned short* __restrict__ wi1f, unsigned short* __restrict__ xaf,
                       unsigned short* __restrict__ h1af){
  __shared__ __align__(4) unsigned short lt[12800];   // [k][c] stride 100
  int tid = threadIdx.x;
  int bx = blockIdx.x;
  if (bx < 128){
    int b = bx;
    unsigned int* l2 = (unsigned int*)lt;
    for (int e4 = tid; e4 < 3072; e4 += 256){
      int k = e4 / 24, c4 = (e4 - k*24)*4;
      const float4 v = *(const float4*)(Tm + k*(HID*CDIM) + b*CDIM + c4);
      int base = (k*100 + c4) >> 1;
      l2[base]   = (unsigned int)f2bf(v.x) | ((unsigned int)f2bf(v.y) << 16);
      l2[base+1] = (unsigned int)f2bf(v.z) | ((unsigned int)f2bf(v.w) << 16);
    }
    __syncthreads();
    unsigned int* tm2 = (unsigned int*)(tmh + b*(HID*CDIM));
    for (int e2 = tid; e2 < 6144; e2 += 256){
      int e = e2*2;
      int chunk = e / 768;
      int r1 = e - chunk*768;
      int c = r1 >> 3, h = r1 & 7;    // h even
      unsigned int lo = lt[(chunk*8 + h)*100 + c];
      unsigned int hi = lt[(chunk*8 + h + 1)*100 + c];
      tm2[e2] = lo | (hi << 16);
    }
  } else if (bx < 132){
    for (int e = (bx-128)*256 + tid; e < 24576; e += 1024){
      int k2 = e / 384, r = e - k2*384;
      whh0p[e] = packh2(whh0[r*128 + 2*k2], whh0[r*128 + 2*k2 + 1]);
      whh1p[e] = packh2(whh1[r*128 + 2*k2], whh1[r*128 + 2*k2 + 1]);
    }
  } else if (bx < 136){
    for (int e = (bx-132)*256 + tid; e < 20480; e += 1024){
      int kc = e >> 10, rem = e & 1023;
      int col = rem >> 3, j = rem & 7;
      w1f[e] = f2bf(w1[col*160 + kc*8 + j]);
    }
  } else if (bx < 140){
    for (int e = (bx-136)*256 + tid; e < 24576; e += 1024){
      int kc = e / 3072, rem = e - kc*3072;
      int col = rem >> 3, kl = rem & 7;
      wi0f[e] = f2bf(wih0[col*64 + kc*8 + kl]);
    }
  } else if (bx < 144){
    for (int e = (bx-140)*256 + tid; e < 49152; e += 1024){
      int kc = e / 3072, rem = e - kc*3072;
      int col = rem >> 3, kl = rem & 7;
      wi1f[e] = f2bf(wih1[col*128 + kc*8 + kl]);
    }
  } else if (bx < 156){
    for (int e = (bx-144)*256 + tid; e < 131072; e += 3072){
      int t = e >> 12, rem = e & 4095;
      int ntile = rem >> 10, rem2 = rem & 1023;
      int kc = rem2 >> 7, nl = (rem2 >> 3) & 15, kl = rem2 & 7;
      int n = ntile*16 + nl, k = kc*8 + kl;
      xaf[e] = f2bf(x[t*4096 + n*64 + k]);
    }
  } else {
    for (int e = (bx-156)*256 + tid; e < 65536; e += 3072){
      int t = e >> 11, rem = e & 2047;
      int n = rem >> 5, c = rem & 31;
      int pos = t*10240 + (n>>4)*2560 + (16 + (c>>3))*128 + (n&15)*8 + (c&7);
      h1af[pos] = f2bf(a[t*(NB*ACT) + n*ACT + c]);
    }
  }
}

// ---------------- gi GEMM (layer-0 input projection) ----------------
template<int KK, int TSU>
__global__ __launch_bounds__(256) void k_gi(const unsigned short* __restrict__ af,
                                            const unsigned short* __restrict__ wf,
                                            const float* __restrict__ bias,
                                            float* __restrict__ gig){
  int t = blockIdx.x, by = blockIdx.y, tid = threadIdx.x;
  int wave = tid >> 6, lane = tid & 63, m = lane & 15, quad = lane >> 4;
  const uint4* A4 = (const uint4*)af;
  const uint4* B4 = (const uint4*)wf;
  uint4 av[KK];
  #pragma unroll
  for (int kk = 0; kk < KK; kk++) av[kk] = A4[t*TSU + wave*(TSU/4) + (kk*4+quad)*16 + m];
  f32x4 acc[6];
  #pragma unroll
  for (int i = 0; i < 6; i++) acc[i] = (f32x4)(0.0f);
  #pragma unroll
  for (int kk = 0; kk < KK; kk++){
    short8 a = __builtin_bit_cast(short8, av[kk]);
    #pragma unroll
    for (int ntl = 0; ntl < 6; ntl++){
      int nt = by*6 + ntl;
      uint4 bv = B4[(kk*4+quad)*384 + nt*16 + m];
      acc[ntl] = __builtin_amdgcn_mfma_f32_16x16x32_bf16(a, __builtin_bit_cast(short8, bv), acc[ntl], 0, 0, 0);
    }
  }
  #pragma unroll
  for (int ntl = 0; ntl < 6; ntl++){
    int col = (by*6+ntl)*16 + m;
    float bv = bias[col];
    #pragma unroll
    for (int rr = 0; rr < 4; rr++){
      int n = wave*16 + quad*4 + rr;
      gig[(t*NB + n)*G3 + col] = acc[ntl][rr] + bv;
    }
  }
}

// ---------------- fused dual-layer GRU: 2 samples per block, phase-shifted ----------------
// Samples share weights (32 words/thread, proven budget). Interval i: dots for
// sample (i&1) on all 12 waves; gates for the OTHER sample (2 waves) hidden under
// the dots issue; ONE barrier per interval => 1 barrier per sample-step (was 2)
// and no idle-block gates phase. 65 intervals cover 64 sample-steps per layer.
__global__ __launch_bounds__(768, 1) void k_rec2(const unsigned int* __restrict__ whh0p,
                                                 const unsigned int* __restrict__ whh1p,
                                                 const float* __restrict__ bhh0,
                                                 const float* __restrict__ bhh1,
                                                 const float* __restrict__ bih1,
                                                 const unsigned short* __restrict__ wi1f,
                                                 const float* __restrict__ gig,
                                                 unsigned short* __restrict__ h1af){
  __shared__ __align__(16) unsigned int hl[2][64];
  __shared__ float A0[2][G3];
  __shared__ __align__(16) float gl[2][T_STEPS*G3];               // 96 KB
  __shared__ __align__(16) unsigned short hist0[2][T_STEPS*136];  // 17 KB
  __shared__ __align__(16) unsigned short hist1[2][T_STEPS*HID];  // 16 KB
  int n0 = blockIdx.x*2, tid = threadIdx.x;
  int r = tid >> 1, kh = tid & 1;
  // stage both samples' gig0 slices (coalesced float4)
  {
    const float4* gg = (const float4*)gig;
    float4* gl4 = (float4*)gl;
    #pragma unroll
    for (int k = 0; k < 8; k++){
      int e = k*768 + tid;            // e < 6144 = 2*32*96
      int s = e / 3072, rem = e - s*3072;
      int t = rem / 96, c = rem - t*96;
      gl4[s*3072 + t*96 + c] = gg[(t*NB + n0 + s)*96 + c];
    }
  }
  unsigned int wh[32];
  #pragma unroll
  for (int i = 0; i < 32; i++) wh[i] = whh0p[(kh*32 + i)*384 + r];
  float bh = (kh == 0) ? bhh0[r] : 0.0f;
  if (tid < 128) ((unsigned int*)hl)[tid] = 0u;
  float hp0 = 0.0f, hp1 = 0.0f;
  __syncthreads();
  // ---- loop 1: layer-0, phase-shifted over 2 samples ----
  for (int i = 0; i <= 2*T_STEPS; i++){
    int s = i & 1, ts = i >> 1;
    if (ts < T_STEPS){
      const uint4* h4s = (const uint4*)(hl[s]);
      float s0 = 0.0f, s1 = 0.0f, s2 = 0.0f, s3 = 0.0f;
      #pragma unroll
      for (int g = 0; g < 2; g++){
        uint4 hv[4];
        #pragma unroll
        for (int j = 0; j < 4; j++) hv[j] = h4s[kh*8 + g*4 + j];
        s0 = dot2f(s0, wh[g*16 + 0], hv[0].x);  s0 = dot2f(s0, wh[g*16 + 1], hv[0].y);
        s0 = dot2f(s0, wh[g*16 + 2], hv[0].z);  s0 = dot2f(s0, wh[g*16 + 3], hv[0].w);
        s1 = dot2f(s1, wh[g*16 + 4], hv[1].x);  s1 = dot2f(s1, wh[g*16 + 5], hv[1].y);
        s1 = dot2f(s1, wh[g*16 + 6], hv[1].z);  s1 = dot2f(s1, wh[g*16 + 7], hv[1].w);
        s2 = dot2f(s2, wh[g*16 + 8], hv[2].x);  s2 = dot2f(s2, wh[g*16 + 9], hv[2].y);
        s2 = dot2f(s2, wh[g*16 +10], hv[2].z);  s2 = dot2f(s2, wh[g*16 +11], hv[2].w);
        s3 = dot2f(s3, wh[g*16 +12], hv[3].x);  s3 = dot2f(s3, wh[g*16 +13], hv[3].y);
        s3 = dot2f(s3, wh[g*16 +14], hv[3].z);  s3 = dot2f(s3, wh[g*16 +15], hv[3].w);
      }
      float gh = bh + ((s0 + s1) + (s2 + s3));
      gh += __shfl_xor(gh, 1);
      if (kh == 0) A0[s][r] = gh;
    }
    int so = s ^ 1, to = (i - 1) >> 1;
    if (i >= 1 && to < T_STEPS && tid < HID){
      const float* gp = gl[so] + to*G3;
      const float* ap = A0[so];
      float rg = sigmoidf_(gp[tid]       + ap[tid]);
      float z  = sigmoidf_(gp[tid+HID]   + ap[tid+HID]);
      float nn = tanhf_   (gp[tid+2*HID] + rg*ap[tid+2*HID]);
      float hp = so ? hp1 : hp0;
      float hn = (1.0f - z)*nn + z*hp;
      if (so) hp1 = hn; else hp0 = hn;
      ((__half*)(hl[so]))[tid] = __float2half_rn(hn);
      hist0[so][to*136 + tid] = f2bf(hn);
    }
    __syncthreads();
  }
  // ---- mid: gi1[s][t][col] = h0 @ wih1^T + bih1 via MFMA, written into gl[s] ----
  {
    int wave = tid >> 6, lane = tid & 63, m = lane & 15, quad = lane >> 4;
    const uint4* B4 = (const uint4*)wi1f;
    int nt0 = wave*2;
    float bv0 = bih1[nt0*16 + m];
    float bv1 = bih1[(nt0+1)*16 + m];
    #pragma unroll
    for (int s = 0; s < 2; s++){
      const uint4* H4 = (const uint4*)(hist0[s]);   // row stride 17 uint4
      f32x4 acc00 = (f32x4)(0.0f), acc01 = (f32x4)(0.0f);
      f32x4 acc10 = (f32x4)(0.0f), acc11 = (f32x4)(0.0f);
      #pragma unroll
      for (int kk = 0; kk < 4; kk++){
        uint4 a0 = H4[m*17 + kk*4 + quad];
        uint4 a1 = H4[(16 + m)*17 + kk*4 + quad];
        uint4 b0 = B4[(kk*4 + quad)*384 + nt0*16 + m];
        uint4 b1 = B4[(kk*4 + quad)*384 + (nt0+1)*16 + m];
        short8 a0s = __builtin_bit_cast(short8, a0);
        short8 a1s = __builtin_bit_cast(short8, a1);
        short8 b0s = __builtin_bit_cast(short8, b0);
        short8 b1s = __builtin_bit_cast(short8, b1);
        acc00 = __builtin_amdgcn_mfma_f32_16x16x32_bf16(a0s, b0s, acc00, 0, 0, 0);
        acc01 = __builtin_amdgcn_mfma_f32_16x16x32_bf16(a0s, b1s, acc01, 0, 0, 0);
        acc10 = __builtin_amdgcn_mfma_f32_16x16x32_bf16(a1s, b0s, acc10, 0, 0, 0);
        acc11 = __builtin_amdgcn_mfma_f32_16x16x32_bf16(a1s, b1s, acc11, 0, 0, 0);
      }
      float* gls = gl[s];
      #pragma unroll
      for (int rr = 0; rr < 4; rr++){
        gls[(quad*4 + rr)*G3 + nt0*16 + m]          = acc00[rr] + bv0;
        gls[(quad*4 + rr)*G3 + (nt0+1)*16 + m]      = acc01[rr] + bv1;
        gls[(16 + quad*4 + rr)*G3 + nt0*16 + m]     = acc10[rr] + bv0;
        gls[(16 + quad*4 + rr)*G3 + (nt0+1)*16 + m] = acc11[rr] + bv1;
      }
    }
  }
  // ---- reload weights for layer 1 (reuse wh[]) ----
  asm volatile("" ::: "memory");
  #pragma unroll
  for (int i = 0; i < 32; i++) wh[i] = whh1p[(kh*32 + i)*384 + r];
  bh = (kh == 0) ? bhh1[r] : 0.0f;
  if (tid < 128) ((unsigned int*)hl)[tid] = 0u;
  hp0 = 0.0f; hp1 = 0.0f;
  __syncthreads();
  // ---- loop 2: layer-1, phase-shifted (gl holds gi1 incl. bias) ----
  for (int i = 0; i <= 2*T_STEPS; i++){
    int s = i & 1, ts = i >> 1;
    if (ts < T_STEPS){
      const uint4* h4s = (const uint4*)(hl[s]);
      float s0 = 0.0f, s1 = 0.0f, s2 = 0.0f, s3 = 0.0f;
      #pragma unroll
      for (int g = 0; g < 2; g++){
        uint4 hv[4];
        #pragma unroll
        for (int j = 0; j < 4; j++) hv[j] = h4s[kh*8 + g*4 + j];
        s0 = dot2f(s0, wh[g*16 + 0], hv[0].x);  s0 = dot2f(s0, wh[g*16 + 1], hv[0].y);
        s0 = dot2f(s0, wh[g*16 + 2], hv[0].z);  s0 = dot2f(s0, wh[g*16 + 3], hv[0].w);
        s1 = dot2f(s1, wh[g*16 + 4], hv[1].x);  s1 = dot2f(s1, wh[g*16 + 5], hv[1].y);
        s1 = dot2f(s1, wh[g*16 + 6], hv[1].z);  s1 = dot2f(s1, wh[g*16 + 7], hv[1].w);
        s2 = dot2f(s2, wh[g*16 + 8], hv[2].x);  s2 = dot2f(s2, wh[g*16 + 9], hv[2].y);
        s2 = dot2f(s2, wh[g*16 +10], hv[2].z);  s2 = dot2f(s2, wh[g*16 +11], hv[2].w);
        s3 = dot2f(s3, wh[g*16 +12], hv[3].x);  s3 = dot2f(s3, wh[g*16 +13], hv[3].y);
        s3 = dot2f(s3, wh[g*16 +14], hv[3].z);  s3 = dot2f(s3, wh[g*16 +15], hv[3].w);
      }
      float gh = bh + ((s0 + s1) + (s2 + s3));
      gh += __shfl_xor(gh, 1);
      if (kh == 0) A0[s][r] = gh;
    }
    int so = s ^ 1, to = (i - 1) >> 1;
    if (i >= 1 && to < T_STEPS && tid < HID){
      const float* gp = gl[so] + to*G3;
      const float* ap = A0[so];
      float rg = sigmoidf_(gp[tid]       + ap[tid]);
      float z  = sigmoidf_(gp[tid+HID]   + ap[tid+HID]);
      float nn = tanhf_   (gp[tid+2*HID] + rg*ap[tid+2*HID]);
      float hp = so ? hp1 : hp0;
      float hn = (1.0f - z)*nn + z*hp;
      if (so) hp1 = hn; else hp0 = hn;
      ((__half*)(hl[so]))[tid] = __float2half_rn(hn);
      hist1[so][to*HID + tid] = f2bf(hn);
    }
    __syncthreads();
  }
  // flush both samples' h1 history (uint4 = 8 bf16), fc1 A-frag layout
  for (int e = tid; e < 2*T_STEPS*16; e += 768){
    int s = e >> 9, rem = e & 511;
    int t = rem >> 4, j = rem & 15;
    int n = n0 + s;
    uint4 v = *(const uint4*)(hist1[s] + t*HID + j*8);
    *(uint4*)(h1af + t*10240 + (n>>4)*2560 + j*128 + (n&15)*8) = v;
  }
}

// ---------------- fc1 ----------------
__global__ __launch_bounds__(256) void k_fc1(const unsigned short* __restrict__ h1af,
                                             const unsigned short* __restrict__ w1f,
                                             const float* __restrict__ b1,
                                             unsigned short* __restrict__ fc1h){
  __shared__ float b1s[128];
  int t = blockIdx.x, tid = threadIdx.x;
  int wave = tid >> 6, lane = tid & 63, m = lane & 15, quad = lane >> 4;
  if (tid < 128) b1s[tid] = b1[tid];
  const uint4* A4 = (const uint4*)(h1af + t*10240);
  const uint4* B4 = (const uint4*)w1f;
  f32x4 acc[8];
  #pragma unroll
  for (int i = 0; i < 8; i++) acc[i] = (f32x4)(0.0f);
  #pragma unroll
  for (int ks = 0; ks < 5; ks++){
    uint4 av = A4[wave*320 + (ks*4 + quad)*16 + m];
    short8 avs = __builtin_bit_cast(short8, av);
    #pragma unroll
    for (int nt = 0; nt < 8; nt++){
      uint4 bv = B4[(ks*4 + quad)*128 + nt*16 + m];
      acc[nt] = __builtin_amdgcn_mfma_f32_16x16x32_bf16(avs, __builtin_bit_cast(short8, bv), acc[nt], 0, 0, 0);
    }
  }
  __syncthreads();
  #pragma unroll
  for (int nt = 0; nt < 8; nt++){
    float bj = b1s[nt*16 + m];
    #pragma unroll
    for (int rr = 0; rr < 4; rr++){
      float v = fmaxf(acc[nt][rr] + bj, 0.0f);
      fc1h[t*8192 + wave*2048 + (nt*2 + (m>>3))*128 + (quad*4 + rr)*8 + (m&7)] = f2bf(v);
    }
  }
}

// ---------------- minibatch discrimination: one block per (b, t) (round-5 proven) ----------------
__global__ __launch_bounds__(256) void k_disc(const unsigned short* __restrict__ fc1h,
                                              const unsigned short* __restrict__ tmh,
                                              float* __restrict__ O){
  __shared__ __align__(16) __half Mh[64*120];     // cols 0..95 = M, 96..103 = S8
  __shared__ unsigned short plist[2016];
  __shared__ float osum[64];
  __shared__ unsigned int cnt;
  int b = blockIdx.x, t = blockIdx.y;
  int tid = threadIdx.x;
  int wave = tid >> 6, lane = tid & 63, m = lane & 15, quad = lane >> 4;
  if (tid < 64) osum[tid] = 0.0f;
  if (tid == 0) cnt = 0u;
  const uint4* Bg = (const uint4*)(tmh + b*(CDIM*HID));
  const uint4* Ag = (const uint4*)(fc1h + t*8192);
  uint4 a4[4];
  #pragma unroll
  for (int kk = 0; kk < 4; kk++) a4[kk] = Ag[wave*256 + (kk*4 + quad)*16 + m];
  f32x4 acc[6];
  #pragma unroll
  for (int i = 0; i < 6; i++) acc[i] = (f32x4)(0.0f);
  #pragma unroll
  for (int kk = 0; kk < 4; kk++){
    short8 av = __builtin_bit_cast(short8, a4[kk]);
    #pragma unroll
    for (int nt = 0; nt < 6; nt++){
      uint4 b4 = Bg[(kk*4 + quad)*96 + nt*16 + m];
      acc[nt] = __builtin_amdgcn_mfma_f32_16x16x32_bf16(av, __builtin_bit_cast(short8, b4), acc[nt], 0, 0, 0);
    }
  }
  #pragma unroll
  for (int nt = 0; nt < 6; nt++){
    #pragma unroll
    for (int rr = 0; rr < 4; rr++){
      Mh[(wave*16 + quad*4 + rr)*120 + nt*16 + m] = __float2half(acc[nt][rr]);
    }
  }
  __syncthreads();
  const unsigned int ONES2 = 0x3C003C00u;  // (1.0h, 1.0h)
  #pragma unroll
  for (int idx = tid; idx < 512; idx += 256){
    int r = idx >> 3, jc = idx & 7;
    const unsigned int* row = (const unsigned int*)(Mh + r*120 + jc*12);
    float s = 0.0f;
    #pragma unroll
    for (int q = 0; q < 6; q++) s = dot2f(s, row[q], ONES2);
    Mh[r*120 + 96 + jc] = __float2half(s);
  }
  __syncthreads();
  const uint4* M4 = (const uint4*)Mh;
  for (int p = tid; p < 2016; p += 256){
    int r = p >> 5, s = p & 31;
    int i, j;
    if (s == 0){ i = 63; j = r; }
    else {
      i = r + s;      if (i >= 63) i -= 63;
      j = r + 63 - s; if (j >= 63) j -= 63;
    }
    uint4 qa = M4[i*15 + 12];
    uint4 qb = M4[j*15 + 12];
    float lb = l1d4(0.0f, qa, qb);
    if (lb <= 14.5f){
      unsigned int k = atomicAdd(&cnt, 1u);
      plist[k] = (unsigned short)(i*64 + j);
    }
  }
  __syncthreads();
  int ns = (int)cnt;
  if (ns > 2016) ns = 2016;
  for (int v = tid; v < ns; v += 256){
    int pr = plist[v];
    int i = pr >> 6, j = pr & 63;
    float L = 0.0f;
    #pragma unroll
    for (int c = 0; c < 12; c++){
      L = l1d4(L, M4[i*15 + c], M4[j*15 + c]);
    }
    float e = __expf(-L);
    atomicAdd(&osum[i], e);
    atomicAdd(&osum[j], e);
  }
  __syncthreads();
  if (tid < 64) O[(t*HID + b)*NB + tid] = osum[tid]*(1.0f/63.0f);
}

// ---------------- final: 4-wave parallel dot ----------------
__global__ __launch_bounds__(256) void k_final(const unsigned short* __restrict__ fc1h,
                                               const float* __restrict__ O,
                                               const float* __restrict__ w2, const float* __restrict__ b2,
                                               float* __restrict__ out){
  __shared__ float ol[NB*HID];
  __shared__ unsigned short fr[8192];
  __shared__ float wl[2*HID + 2];
  __shared__ float pp[4][NB];
  int t = blockIdx.x, tid = threadIdx.x;
  for (int i = tid; i < NB*HID; i += 256) ol[i] = O[t*NB*HID + i];
  const uint4* Fg = (const uint4*)(fc1h + t*8192);
  for (int i = tid; i < 1024; i += 256) ((uint4*)fr)[i] = Fg[i];
  if (tid < 2*HID) wl[tid] = w2[tid];
  if (tid == 0) wl[2*HID] = b2[0];
  __syncthreads();
  int n = tid & 63, part = tid >> 6;
  float acc = 0.0f;
  int base = (n>>4)*2048 + (n&15)*8;
  #pragma unroll
  for (int jc = 0; jc < 4; jc++){
    int j8 = part*4 + jc;
    #pragma unroll
    for (int k = 0; k < 8; k++)
      acc += bf2f(fr[base + j8*128 + k])*wl[j8*8 + k];
  }
  #pragma unroll 8
  for (int bb = 0; bb < 32; bb++){
    int bq = part*32 + bb;
    acc += ol[bq*NB + n]*wl[HID + bq];
  }
  pp[part][n] = acc;
  __syncthreads();
  if (tid < NB){
    float s = wl[2*HID] + pp[0][tid] + pp[1][tid] + pp[2][tid] + pp[3][tid];
    out[t*NB + tid] = sigmoidf_(s);
  }
}

extern "C" void kernel_launch(void* const* d_in, const int* in_sizes, int n_in,
                              void* d_out, int out_size, void* d_ws, size_t ws_size,
                              hipStream_t stream){
  const float* x    = (const float*)d_in[0];
  const float* a    = (const float*)d_in[1];
  const float* wih0 = (const float*)d_in[2];
  const float* whh0 = (const float*)d_in[3];
  const float* bih0 = (const float*)d_in[4];
  const float* bhh0 = (const float*)d_in[5];
  const float* wih1 = (const float*)d_in[6];
  const float* whh1 = (const float*)d_in[7];
  const float* bih1 = (const float*)d_in[8];
  const float* bhh1 = (const float*)d_in[9];
  const float* w1   = (const float*)d_in[10];
  const float* b1   = (const float*)d_in[11];
  const float* w2   = (const float*)d_in[12];
  const float* b2   = (const float*)d_in[13];
  const float* Tm   = (const float*)d_in[14];
  float* ws = (float*)d_ws;
  float* Ows = ws;                                          // 262144 floats
  unsigned int* whh0p = (unsigned int*)(ws + 262144);       // 24576 dwords
  unsigned int* whh1p = (unsigned int*)(ws + 286720);       // 24576
  unsigned short* tmh  = (unsigned short*)(ws + 311296);    // 1572864 ushorts
  unsigned short* fc1h = (unsigned short*)(ws + 1097728);   // 262144 ushorts
  unsigned short* h1af = (unsigned short*)(ws + 1228800);   // 327680 ushorts
  unsigned short* w1f  = (unsigned short*)(ws + 1392640);   // 20480 ushorts
  unsigned short* xaf  = (unsigned short*)(ws + 1402880);   // 131072 ushorts
  unsigned short* wi0f = (unsigned short*)(ws + 1468416);   // 24576 ushorts
  unsigned short* wi1f = (unsigned short*)(ws + 1480704);   // 49152 ushorts
  float* gig = ws + 1636352;                                // 786432 floats
  float* out = (float*)d_out;

  k_prep<<<dim3(168), dim3(256), 0, stream>>>(Tm, tmh, whh0, whh1, w1, wih0, wih1, x, a,
                                              whh0p, whh1p, w1f, wi0f, wi1f, xaf, h1af);
  k_gi<2, 512><<<dim3(T_STEPS, 4), dim3(256), 0, stream>>>(xaf, wi0f, bih0, gig);
  k_rec2<<<dim3(NB/2), dim3(768), 0, stream>>>(whh0p, whh1p, bhh0, bhh1, bih1, wi1f, gig, h1af);
  k_fc1<<<dim3(T_STEPS), dim3(256), 0, stream>>>(h1af, w1f, b1, fc1h);
  k_disc<<<dim3(HID, T_STEPS), dim3(256), 0, stream>>>(fc1h, tmh, Ows);
  k_final<<<dim3(T_STEPS), dim3(256), 0, stream>>>(fc1h, Ows, w2, b2, out);
}

// Round 16
// 181.174 us; speedup vs baseline: 1.1455x; 1.1455x over previous
//
#include <hip/hip_runtime.h>
#include <hip/hip_fp16.h>
#include <cstdint>

#define T_STEPS 32
#define NB 64
#define STATE 64
#define HID 128
#define ACT 32
#define CDIM 96
#define G3 (3*HID)   // 384

typedef __attribute__((ext_vector_type(8))) short short8;
typedef __attribute__((ext_vector_type(4))) float f32x4;
typedef _Float16 h2v __attribute__((ext_vector_type(2)));

__device__ __forceinline__ unsigned short f2bf(float f){
  unsigned int u = __builtin_bit_cast(unsigned int, f);
  u = u + 0x7FFFu + ((u >> 16) & 1u);
  return (unsigned short)(u >> 16);
}
__device__ __forceinline__ float bf2f(unsigned short u){
  unsigned int v = ((unsigned int)u) << 16; return __builtin_bit_cast(float, v);
}
__device__ __forceinline__ unsigned int packh2(float f0, float f1){
  return (unsigned int)__half_as_ushort(__float2half_rn(f0)) |
         ((unsigned int)__half_as_ushort(__float2half_rn(f1)) << 16);
}
__device__ __forceinline__ float sigmoidf_(float x){ return 1.0f/(1.0f + __expf(-x)); }
__device__ __forceinline__ float tanhf_(float x){ float e = __expf(2.0f*x); return (e-1.0f)/(e+1.0f); }

__device__ __forceinline__ float dot2f(float acc, unsigned int a, unsigned int b){
  h2v av = __builtin_bit_cast(h2v, a);
  h2v bv = __builtin_bit_cast(h2v, b);
  return __builtin_amdgcn_fdot2(av, bv, acc, false);
}
__device__ __forceinline__ float l1d(float acc, unsigned int ua, unsigned int ub){
  __half2 a = __builtin_bit_cast(__half2, ua);
  __half2 b = __builtin_bit_cast(__half2, ub);
  __half2 d = __habs2(__hsub2(a, b));
  h2v dv = __builtin_bit_cast(h2v, d);
  h2v ones; ones[0] = (_Float16)1.0f; ones[1] = (_Float16)1.0f;
  return __builtin_amdgcn_fdot2(dv, ones, acc, false);
}
__device__ __forceinline__ float l1d4(float acc, uint4 a, uint4 b){
  acc = l1d(acc, a.x, b.x); acc = l1d(acc, a.y, b.y);
  acc = l1d(acc, a.z, b.z); acc = l1d(acc, a.w, b.w);
  return acc;
}

// ---------------- prep ----------------
__global__ void k_prep(const float* __restrict__ Tm, unsigned short* __restrict__ tmh,
                       const float* __restrict__ whh0, const float* __restrict__ whh1,
                       const float* __restrict__ w1, const float* __restrict__ wih0,
                       const float* __restrict__ wih1, const float* __restrict__ x,
                       const float* __restrict__ a,
                       unsigned int* __restrict__ whh0p, unsigned int* __restrict__ whh1p,
                       unsigned short* __restrict__ w1f, unsigned short* __restrict__ wi0f,
                       unsigned short* __restrict__ wi1f, unsigned short* __restrict__ xaf,
                       unsigned short* __restrict__ h1af){
  __shared__ __align__(4) unsigned short lt[12800];   // [k][c] stride 100
  int tid = threadIdx.x;
  int bx = blockIdx.x;
  if (bx < 128){
    int b = bx;
    unsigned int* l2 = (unsigned int*)lt;
    for (int e4 = tid; e4 < 3072; e4 += 256){
      int k = e4 / 24, c4 = (e4 - k*24)*4;
      const float4 v = *(const float4*)(Tm + k*(HID*CDIM) + b*CDIM + c4);
      int base = (k*100 + c4) >> 1;
      l2[base]   = (unsigned int)f2bf(v.x) | ((unsigned int)f2bf(v.y) << 16);
      l2[base+1] = (unsigned int)f2bf(v.z) | ((unsigned int)f2bf(v.w) << 16);
    }
    __syncthreads();
    unsigned int* tm2 = (unsigned int*)(tmh + b*(HID*CDIM));
    for (int e2 = tid; e2 < 6144; e2 += 256){
      int e = e2*2;
      int chunk = e / 768;
      int r1 = e - chunk*768;
      int c = r1 >> 3, h = r1 & 7;    // h even
      unsigned int lo = lt[(chunk*8 + h)*100 + c];
      unsigned int hi = lt[(chunk*8 + h + 1)*100 + c];
      tm2[e2] = lo | (hi << 16);
    }
  } else if (bx < 132){
    for (int e = (bx-128)*256 + tid; e < 24576; e += 1024){
      int k2 = e / 384, r = e - k2*384;
      whh0p[e] = packh2(whh0[r*128 + 2*k2], whh0[r*128 + 2*k2 + 1]);
      whh1p[e] = packh2(whh1[r*128 + 2*k2], whh1[r*128 + 2*k2 + 1]);
    }
  } else if (bx < 136){
    for (int e = (bx-132)*256 + tid; e < 20480; e += 1024){
      int kc = e >> 10, rem = e & 1023;
      int col = rem >> 3, j = rem & 7;
      w1f[e] = f2bf(w1[col*160 + kc*8 + j]);
    }
  } else if (bx < 140){
    for (int e = (bx-136)*256 + tid; e < 24576; e += 1024){
      int kc = e / 3072, rem = e - kc*3072;
      int col = rem >> 3, kl = rem & 7;
      wi0f[e] = f2bf(wih0[col*64 + kc*8 + kl]);
    }
  } else if (bx < 144){
    for (int e = (bx-140)*256 + tid; e < 49152; e += 1024){
      int kc = e / 3072, rem = e - kc*3072;
      int col = rem >> 3, kl = rem & 7;
      wi1f[e] = f2bf(wih1[col*128 + kc*8 + kl]);
    }
  } else if (bx < 156){
    for (int e = (bx-144)*256 + tid; e < 131072; e += 3072){
      int t = e >> 12, rem = e & 4095;
      int ntile = rem >> 10, rem2 = rem & 1023;
      int kc = rem2 >> 7, nl = (rem2 >> 3) & 15, kl = rem2 & 7;
      int n = ntile*16 + nl, k = kc*8 + kl;
      xaf[e] = f2bf(x[t*4096 + n*64 + k]);
    }
  } else {
    for (int e = (bx-156)*256 + tid; e < 65536; e += 3072){
      int t = e >> 11, rem = e & 2047;
      int n = rem >> 5, c = rem & 31;
      int pos = t*10240 + (n>>4)*2560 + (16 + (c>>3))*128 + (n&15)*8 + (c&7);
      h1af[pos] = f2bf(a[t*(NB*ACT) + n*ACT + c]);
    }
  }
}

// ---------------- gi GEMM (layer-0 input projection) ----------------
template<int KK, int TSU>
__global__ __launch_bounds__(256) void k_gi(const unsigned short* __restrict__ af,
                                            const unsigned short* __restrict__ wf,
                                            const float* __restrict__ bias,
                                            float* __restrict__ gig){
  int t = blockIdx.x, by = blockIdx.y, tid = threadIdx.x;
  int wave = tid >> 6, lane = tid & 63, m = lane & 15, quad = lane >> 4;
  const uint4* A4 = (const uint4*)af;
  const uint4* B4 = (const uint4*)wf;
  uint4 av[KK];
  #pragma unroll
  for (int kk = 0; kk < KK; kk++) av[kk] = A4[t*TSU + wave*(TSU/4) + (kk*4+quad)*16 + m];
  f32x4 acc[6];
  #pragma unroll
  for (int i = 0; i < 6; i++) acc[i] = (f32x4)(0.0f);
  #pragma unroll
  for (int kk = 0; kk < KK; kk++){
    short8 a = __builtin_bit_cast(short8, av[kk]);
    #pragma unroll
    for (int ntl = 0; ntl < 6; ntl++){
      int nt = by*6 + ntl;
      uint4 bv = B4[(kk*4+quad)*384 + nt*16 + m];
      acc[ntl] = __builtin_amdgcn_mfma_f32_16x16x32_bf16(a, __builtin_bit_cast(short8, bv), acc[ntl], 0, 0, 0);
    }
  }
  #pragma unroll
  for (int ntl = 0; ntl < 6; ntl++){
    int col = (by*6+ntl)*16 + m;
    float bv = bias[col];
    #pragma unroll
    for (int rr = 0; rr < 4; rr++){
      int n = wave*16 + quad*4 + rr;
      gig[(t*NB + n)*G3 + col] = acc[ntl][rr] + bv;
    }
  }
}

// ---------------- fused dual-layer GRU: loop1 -> mid MFMA (gi1) -> loop2 (round-13 proven) ----------------
__global__ __launch_bounds__(768, 3) void k_rec2(const unsigned int* __restrict__ whh0p,
                                                 const unsigned int* __restrict__ whh1p,
                                                 const float* __restrict__ bhh0,
                                                 const float* __restrict__ bhh1,
                                                 const float* __restrict__ bih1,
                                                 const unsigned short* __restrict__ wi1f,
                                                 const float* __restrict__ gig,
                                                 unsigned short* __restrict__ h1af){
  __shared__ __align__(16) unsigned int hl[64];
  __shared__ float A0[G3];
  __shared__ __align__(16) float gl[T_STEPS*G3];               // 48 KB
  __shared__ __align__(16) unsigned short hist0[T_STEPS*136];  // h0 bf16, rows padded to 136
  __shared__ __align__(16) unsigned short hist1[T_STEPS*HID];  // 8 KB
  int n = blockIdx.x, tid = threadIdx.x;
  int r = tid >> 1, kh = tid & 1;
  {
    const float4* gg = (const float4*)gig;
    float4* gl4 = (float4*)gl;
    #pragma unroll
    for (int k = 0; k < 4; k++){
      int e = k*768 + tid;            // e < 3072 = 32*96
      int t = e / 96, c = e - t*96;
      gl4[t*96 + c] = gg[(t*NB + n)*96 + c];
    }
  }
  unsigned int wh[32];
  #pragma unroll
  for (int i = 0; i < 32; i++) wh[i] = whh0p[(kh*32 + i)*384 + r];
  float bh = (kh == 0) ? bhh0[r] : 0.0f;
  if (tid < 64) hl[tid] = 0u;
  float hprev = 0.0f;
  __syncthreads();
  const uint4* h4 = (const uint4*)hl;
  // ---- loop 1: layer-0 recurrence ----
  for (int t = 0; t < T_STEPS; t++){
    float s0 = 0.0f, s1 = 0.0f, s2 = 0.0f, s3 = 0.0f;
    #pragma unroll
    for (int g = 0; g < 2; g++){
      uint4 hv[4];
      #pragma unroll
      for (int j = 0; j < 4; j++) hv[j] = h4[kh*8 + g*4 + j];
      s0 = dot2f(s0, wh[g*16 + 0], hv[0].x);  s0 = dot2f(s0, wh[g*16 + 1], hv[0].y);
      s0 = dot2f(s0, wh[g*16 + 2], hv[0].z);  s0 = dot2f(s0, wh[g*16 + 3], hv[0].w);
      s1 = dot2f(s1, wh[g*16 + 4], hv[1].x);  s1 = dot2f(s1, wh[g*16 + 5], hv[1].y);
      s1 = dot2f(s1, wh[g*16 + 6], hv[1].z);  s1 = dot2f(s1, wh[g*16 + 7], hv[1].w);
      s2 = dot2f(s2, wh[g*16 + 8], hv[2].x);  s2 = dot2f(s2, wh[g*16 + 9], hv[2].y);
      s2 = dot2f(s2, wh[g*16 +10], hv[2].z);  s2 = dot2f(s2, wh[g*16 +11], hv[2].w);
      s3 = dot2f(s3, wh[g*16 +12], hv[3].x);  s3 = dot2f(s3, wh[g*16 +13], hv[3].y);
      s3 = dot2f(s3, wh[g*16 +14], hv[3].z);  s3 = dot2f(s3, wh[g*16 +15], hv[3].w);
    }
    float gh = bh + ((s0 + s1) + (s2 + s3));
    gh += __shfl_xor(gh, 1);
    if (kh == 0) A0[r] = gh;
    __syncthreads();
    if (tid < HID){
      const float* gp = gl + t*G3;
      float rg = sigmoidf_(gp[tid]       + A0[tid]);
      float z  = sigmoidf_(gp[tid+HID]   + A0[tid+HID]);
      float nn = tanhf_   (gp[tid+2*HID] + rg*A0[tid+2*HID]);
      float hn = (1.0f - z)*nn + z*hprev;
      hprev = hn;
      ((__half*)hl)[tid] = __float2half_rn(hn);
      hist0[t*136 + tid] = f2bf(hn);
    }
    __syncthreads();
  }
  // ---- mid: gi1[t][col] = h0 @ wih1^T + bih1 via MFMA, written into gl ----
  {
    int wave = tid >> 6, lane = tid & 63, m = lane & 15, quad = lane >> 4;
    const uint4* B4 = (const uint4*)wi1f;
    const uint4* H4 = (const uint4*)hist0;   // row stride 17 uint4 (136 ushorts)
    f32x4 acc00 = (f32x4)(0.0f), acc01 = (f32x4)(0.0f);
    f32x4 acc10 = (f32x4)(0.0f), acc11 = (f32x4)(0.0f);
    int nt0 = wave*2;
    #pragma unroll
    for (int kk = 0; kk < 4; kk++){
      uint4 a0 = H4[m*17 + kk*4 + quad];          // t-tile 0: rows 0..15
      uint4 a1 = H4[(16 + m)*17 + kk*4 + quad];   // t-tile 1: rows 16..31
      uint4 b0 = B4[(kk*4 + quad)*384 + nt0*16 + m];
      uint4 b1 = B4[(kk*4 + quad)*384 + (nt0+1)*16 + m];
      short8 a0s = __builtin_bit_cast(short8, a0);
      short8 a1s = __builtin_bit_cast(short8, a1);
      short8 b0s = __builtin_bit_cast(short8, b0);
      short8 b1s = __builtin_bit_cast(short8, b1);
      acc00 = __builtin_amdgcn_mfma_f32_16x16x32_bf16(a0s, b0s, acc00, 0, 0, 0);
      acc01 = __builtin_amdgcn_mfma_f32_16x16x32_bf16(a0s, b1s, acc01, 0, 0, 0);
      acc10 = __builtin_amdgcn_mfma_f32_16x16x32_bf16(a1s, b0s, acc10, 0, 0, 0);
      acc11 = __builtin_amdgcn_mfma_f32_16x16x32_bf16(a1s, b1s, acc11, 0, 0, 0);
    }
    float bv0 = bih1[nt0*16 + m];
    float bv1 = bih1[(nt0+1)*16 + m];
    #pragma unroll
    for (int rr = 0; rr < 4; rr++){
      gl[(quad*4 + rr)*G3 + nt0*16 + m]        = acc00[rr] + bv0;
      gl[(quad*4 + rr)*G3 + (nt0+1)*16 + m]    = acc01[rr] + bv1;
      gl[(16 + quad*4 + rr)*G3 + nt0*16 + m]   = acc10[rr] + bv0;
      gl[(16 + quad*4 + rr)*G3 + (nt0+1)*16 + m] = acc11[rr] + bv1;
    }
  }
  // ---- reload weights for layer 1 (reuse wh[]) ----
  asm volatile("" ::: "memory");
  #pragma unroll
  for (int i = 0; i < 32; i++) wh[i] = whh1p[(kh*32 + i)*384 + r];
  bh = (kh == 0) ? bhh1[r] : 0.0f;
  if (tid < 64) hl[tid] = 0u;
  hprev = 0.0f;
  __syncthreads();
  // ---- loop 2: layer-1 recurrence (gl holds gi1 incl. bias) ----
  for (int t = 0; t < T_STEPS; t++){
    float s0 = 0.0f, s1 = 0.0f, s2 = 0.0f, s3 = 0.0f;
    #pragma unroll
    for (int g = 0; g < 2; g++){
      uint4 hv[4];
      #pragma unroll
      for (int j = 0; j < 4; j++) hv[j] = h4[kh*8 + g*4 + j];
      s0 = dot2f(s0, wh[g*16 + 0], hv[0].x);  s0 = dot2f(s0, wh[g*16 + 1], hv[0].y);
      s0 = dot2f(s0, wh[g*16 + 2], hv[0].z);  s0 = dot2f(s0, wh[g*16 + 3], hv[0].w);
      s1 = dot2f(s1, wh[g*16 + 4], hv[1].x);  s1 = dot2f(s1, wh[g*16 + 5], hv[1].y);
      s1 = dot2f(s1, wh[g*16 + 6], hv[1].z);  s1 = dot2f(s1, wh[g*16 + 7], hv[1].w);
      s2 = dot2f(s2, wh[g*16 + 8], hv[2].x);  s2 = dot2f(s2, wh[g*16 + 9], hv[2].y);
      s2 = dot2f(s2, wh[g*16 +10], hv[2].z);  s2 = dot2f(s2, wh[g*16 +11], hv[2].w);
      s3 = dot2f(s3, wh[g*16 +12], hv[3].x);  s3 = dot2f(s3, wh[g*16 +13], hv[3].y);
      s3 = dot2f(s3, wh[g*16 +14], hv[3].z);  s3 = dot2f(s3, wh[g*16 +15], hv[3].w);
    }
    float gh = bh + ((s0 + s1) + (s2 + s3));
    gh += __shfl_xor(gh, 1);
    if (kh == 0) A0[r] = gh;
    __syncthreads();
    if (tid < HID){
      const float* gp = gl + t*G3;
      float rg = sigmoidf_(gp[tid]       + A0[tid]);
      float z  = sigmoidf_(gp[tid+HID]   + A0[tid+HID]);
      float nn = tanhf_   (gp[tid+2*HID] + rg*A0[tid+2*HID]);
      float hn = (1.0f - z)*nn + z*hprev;
      hprev = hn;
      ((__half*)hl)[tid] = __float2half_rn(hn);
      hist1[t*HID + tid] = f2bf(hn);
    }
    __syncthreads();
  }
  // flush h1 history (uint4 = 8 bf16), layout matches fc1's A-frags
  if (tid < T_STEPS*16){
    int t = tid >> 4, j = tid & 15;
    uint4 v = *(const uint4*)(hist1 + t*HID + j*8);
    *(uint4*)(h1af + t*10240 + (n>>4)*2560 + j*128 + (n&15)*8) = v;
  }
}

// ---------------- fc1 ----------------
__global__ __launch_bounds__(256) void k_fc1(const unsigned short* __restrict__ h1af,
                                             const unsigned short* __restrict__ w1f,
                                             const float* __restrict__ b1,
                                             unsigned short* __restrict__ fc1h){
  __shared__ float b1s[128];
  int t = blockIdx.x, tid = threadIdx.x;
  int wave = tid >> 6, lane = tid & 63, m = lane & 15, quad = lane >> 4;
  if (tid < 128) b1s[tid] = b1[tid];
  const uint4* A4 = (const uint4*)(h1af + t*10240);
  const uint4* B4 = (const uint4*)w1f;
  f32x4 acc[8];
  #pragma unroll
  for (int i = 0; i < 8; i++) acc[i] = (f32x4)(0.0f);
  #pragma unroll
  for (int ks = 0; ks < 5; ks++){
    uint4 av = A4[wave*320 + (ks*4 + quad)*16 + m];
    short8 avs = __builtin_bit_cast(short8, av);
    #pragma unroll
    for (int nt = 0; nt < 8; nt++){
      uint4 bv = B4[(ks*4 + quad)*128 + nt*16 + m];
      acc[nt] = __builtin_amdgcn_mfma_f32_16x16x32_bf16(avs, __builtin_bit_cast(short8, bv), acc[nt], 0, 0, 0);
    }
  }
  __syncthreads();
  #pragma unroll
  for (int nt = 0; nt < 8; nt++){
    float bj = b1s[nt*16 + m];
    #pragma unroll
    for (int rr = 0; rr < 4; rr++){
      float v = fmaxf(acc[nt][rr] + bj, 0.0f);
      fc1h[t*8192 + wave*2048 + (nt*2 + (m>>3))*128 + (quad*4 + rr)*8 + (m&7)] = f2bf(v);
    }
  }
}

// ---------------- minibatch discrimination: one block per (b, t) (round-5 proven) ----------------
__global__ __launch_bounds__(256) void k_disc(const unsigned short* __restrict__ fc1h,
                                              const unsigned short* __restrict__ tmh,
                                              float* __restrict__ O){
  __shared__ __align__(16) __half Mh[64*120];     // cols 0..95 = M, 96..103 = S8
  __shared__ unsigned short plist[2016];
  __shared__ float osum[64];
  __shared__ unsigned int cnt;
  int b = blockIdx.x, t = blockIdx.y;
  int tid = threadIdx.x;
  int wave = tid >> 6, lane = tid & 63, m = lane & 15, quad = lane >> 4;
  if (tid < 64) osum[tid] = 0.0f;
  if (tid == 0) cnt = 0u;
  const uint4* Bg = (const uint4*)(tmh + b*(CDIM*HID));
  const uint4* Ag = (const uint4*)(fc1h + t*8192);
  uint4 a4[4];
  #pragma unroll
  for (int kk = 0; kk < 4; kk++) a4[kk] = Ag[wave*256 + (kk*4 + quad)*16 + m];
  f32x4 acc[6];
  #pragma unroll
  for (int i = 0; i < 6; i++) acc[i] = (f32x4)(0.0f);
  #pragma unroll
  for (int kk = 0; kk < 4; kk++){
    short8 av = __builtin_bit_cast(short8, a4[kk]);
    #pragma unroll
    for (int nt = 0; nt < 6; nt++){
      uint4 b4 = Bg[(kk*4 + quad)*96 + nt*16 + m];
      acc[nt] = __builtin_amdgcn_mfma_f32_16x16x32_bf16(av, __builtin_bit_cast(short8, b4), acc[nt], 0, 0, 0);
    }
  }
  #pragma unroll
  for (int nt = 0; nt < 6; nt++){
    #pragma unroll
    for (int rr = 0; rr < 4; rr++){
      Mh[(wave*16 + quad*4 + rr)*120 + nt*16 + m] = __float2half(acc[nt][rr]);
    }
  }
  __syncthreads();
  const unsigned int ONES2 = 0x3C003C00u;  // (1.0h, 1.0h)
  #pragma unroll
  for (int idx = tid; idx < 512; idx += 256){
    int r = idx >> 3, jc = idx & 7;
    const unsigned int* row = (const unsigned int*)(Mh + r*120 + jc*12);
    float s = 0.0f;
    #pragma unroll
    for (int q = 0; q < 6; q++) s = dot2f(s, row[q], ONES2);
    Mh[r*120 + 96 + jc] = __float2half(s);
  }
  __syncthreads();
  const uint4* M4 = (const uint4*)Mh;
  for (int p = tid; p < 2016; p += 256){
    int r = p >> 5, s = p & 31;
    int i, j;
    if (s == 0){ i = 63; j = r; }
    else {
      i = r + s;      if (i >= 63) i -= 63;
      j = r + 63 - s; if (j >= 63) j -= 63;
    }
    uint4 qa = M4[i*15 + 12];
    uint4 qb = M4[j*15 + 12];
    float lb = l1d4(0.0f, qa, qb);
    if (lb <= 14.5f){
      unsigned int k = atomicAdd(&cnt, 1u);
      plist[k] = (unsigned short)(i*64 + j);
    }
  }
  __syncthreads();
  int ns = (int)cnt;
  if (ns > 2016) ns = 2016;
  for (int v = tid; v < ns; v += 256){
    int pr = plist[v];
    int i = pr >> 6, j = pr & 63;
    float L = 0.0f;
    #pragma unroll
    for (int c = 0; c < 12; c++){
      L = l1d4(L, M4[i*15 + c], M4[j*15 + c]);
    }
    float e = __expf(-L);
    atomicAdd(&osum[i], e);
    atomicAdd(&osum[j], e);
  }
  __syncthreads();
  if (tid < 64) O[(t*HID + b)*NB + tid] = osum[tid]*(1.0f/63.0f);
}

// ---------------- final: 4-wave parallel dot ----------------
__global__ __launch_bounds__(256) void k_final(const unsigned short* __restrict__ fc1h,
                                               const float* __restrict__ O,
                                               const float* __restrict__ w2, const float* __restrict__ b2,
                                               float* __restrict__ out){
  __shared__ float ol[NB*HID];
  __shared__ unsigned short fr[8192];
  __shared__ float wl[2*HID + 2];
  __shared__ float pp[4][NB];
  int t = blockIdx.x, tid = threadIdx.x;
  for (int i = tid; i < NB*HID; i += 256) ol[i] = O[t*NB*HID + i];
  const uint4* Fg = (const uint4*)(fc1h + t*8192);
  for (int i = tid; i < 1024; i += 256) ((uint4*)fr)[i] = Fg[i];
  if (tid < 2*HID) wl[tid] = w2[tid];
  if (tid == 0) wl[2*HID] = b2[0];
  __syncthreads();
  int n = tid & 63, part = tid >> 6;
  float acc = 0.0f;
  int base = (n>>4)*2048 + (n&15)*8;
  #pragma unroll
  for (int jc = 0; jc < 4; jc++){
    int j8 = part*4 + jc;
    #pragma unroll
    for (int k = 0; k < 8; k++)
      acc += bf2f(fr[base + j8*128 + k])*wl[j8*8 + k];
  }
  #pragma unroll 8
  for (int bb = 0; bb < 32; bb++){
    int bq = part*32 + bb;
    acc += ol[bq*NB + n]*wl[HID + bq];
  }
  pp[part][n] = acc;
  __syncthreads();
  if (tid < NB){
    float s = wl[2*HID] + pp[0][tid] + pp[1][tid] + pp[2][tid] + pp[3][tid];
    out[t*NB + tid] = sigmoidf_(s);
  }
}

extern "C" void kernel_launch(void* const* d_in, const int* in_sizes, int n_in,
                              void* d_out, int out_size, void* d_ws, size_t ws_size,
                              hipStream_t stream){
  const float* x    = (const float*)d_in[0];
  const float* a    = (const float*)d_in[1];
  const float* wih0 = (const float*)d_in[2];
  const float* whh0 = (const float*)d_in[3];
  const float* bih0 = (const float*)d_in[4];
  const float* bhh0 = (const float*)d_in[5];
  const float* wih1 = (const float*)d_in[6];
  const float* whh1 = (const float*)d_in[7];
  const float* bih1 = (const float*)d_in[8];
  const float* bhh1 = (const float*)d_in[9];
  const float* w1   = (const float*)d_in[10];
  const float* b1   = (const float*)d_in[11];
  const float* w2   = (const float*)d_in[12];
  const float* b2   = (const float*)d_in[13];
  const float* Tm   = (const float*)d_in[14];
  float* ws = (float*)d_ws;
  float* Ows = ws;                                          // 262144 floats
  unsigned int* whh0p = (unsigned int*)(ws + 262144);       // 24576 dwords
  unsigned int* whh1p = (unsigned int*)(ws + 286720);       // 24576
  unsigned short* tmh  = (unsigned short*)(ws + 311296);    // 1572864 ushorts
  unsigned short* fc1h = (unsigned short*)(ws + 1097728);   // 262144 ushorts
  unsigned short* h1af = (unsigned short*)(ws + 1228800);   // 327680 ushorts
  unsigned short* w1f  = (unsigned short*)(ws + 1392640);   // 20480 ushorts
  unsigned short* xaf  = (unsigned short*)(ws + 1402880);   // 131072 ushorts
  unsigned short* wi0f = (unsigned short*)(ws + 1468416);   // 24576 ushorts
  unsigned short* wi1f = (unsigned short*)(ws + 1480704);   // 49152 ushorts
  float* gig = ws + 1636352;                                // 786432 floats
  float* out = (float*)d_out;

  k_prep<<<dim3(168), dim3(256), 0, stream>>>(Tm, tmh, whh0, whh1, w1, wih0, wih1, x, a,
                                              whh0p, whh1p, w1f, wi0f, wi1f, xaf, h1af);
  k_gi<2, 512><<<dim3(T_STEPS, 4), dim3(256), 0, stream>>>(xaf, wi0f, bih0, gig);
  k_rec2<<<dim3(NB), dim3(768), 0, stream>>>(whh0p, whh1p, bhh0, bhh1, bih1, wi1f, gig, h1af);
  k_fc1<<<dim3(T_STEPS), dim3(256), 0, stream>>>(h1af, w1f, b1, fc1h);
  k_disc<<<dim3(HID, T_STEPS), dim3(256), 0, stream>>>(fc1h, tmh, Ows);
  k_final<<<dim3(T_STEPS), dim3(256), 0, stream>>>(fc1h, Ows, w2, b2, out);
}

// Round 17
// 176.585 us; speedup vs baseline: 1.1753x; 1.0260x over previous
//
#include <hip/hip_runtime.h>
#include <hip/hip_fp16.h>
#include <cstdint>

#define T_STEPS 32
#define NB 64
#define STATE 64
#define HID 128
#define ACT 32
#define CDIM 96
#define G3 (3*HID)   // 384

typedef __attribute__((ext_vector_type(8))) short short8;
typedef __attribute__((ext_vector_type(4))) float f32x4;
typedef _Float16 h2v __attribute__((ext_vector_type(2)));

__device__ __forceinline__ unsigned short f2bf(float f){
  unsigned int u = __builtin_bit_cast(unsigned int, f);
  u = u + 0x7FFFu + ((u >> 16) & 1u);
  return (unsigned short)(u >> 16);
}
__device__ __forceinline__ float bf2f(unsigned short u){
  unsigned int v = ((unsigned int)u) << 16; return __builtin_bit_cast(float, v);
}
__device__ __forceinline__ unsigned int packh2(float f0, float f1){
  return (unsigned int)__half_as_ushort(__float2half_rn(f0)) |
         ((unsigned int)__half_as_ushort(__float2half_rn(f1)) << 16);
}
__device__ __forceinline__ float sigmoidf_(float x){ return 1.0f/(1.0f + __expf(-x)); }
__device__ __forceinline__ float tanhf_(float x){ float e = __expf(2.0f*x); return (e-1.0f)/(e+1.0f); }

__device__ __forceinline__ float dot2f(float acc, unsigned int a, unsigned int b){
  h2v av = __builtin_bit_cast(h2v, a);
  h2v bv = __builtin_bit_cast(h2v, b);
  return __builtin_amdgcn_fdot2(av, bv, acc, false);
}
__device__ __forceinline__ float l1d(float acc, unsigned int ua, unsigned int ub){
  __half2 a = __builtin_bit_cast(__half2, ua);
  __half2 b = __builtin_bit_cast(__half2, ub);
  __half2 d = __habs2(__hsub2(a, b));
  h2v dv = __builtin_bit_cast(h2v, d);
  h2v ones; ones[0] = (_Float16)1.0f; ones[1] = (_Float16)1.0f;
  return __builtin_amdgcn_fdot2(dv, ones, acc, false);
}
__device__ __forceinline__ float l1d4(float acc, uint4 a, uint4 b){
  acc = l1d(acc, a.x, b.x); acc = l1d(acc, a.y, b.y);
  acc = l1d(acc, a.z, b.z); acc = l1d(acc, a.w, b.w);
  return acc;
}

// ---------------- prep ----------------
// xnf: n-major x copy for k_rec2's gi0 prologue MFMA. Layout: [n][t][k] bf16
// (row stride 64 = 8 uint4), so A-frag load is X4[(tt*16+m)*8 + kk*4 + quad].
__global__ void k_prep(const float* __restrict__ Tm, unsigned short* __restrict__ tmh,
                       const float* __restrict__ whh0, const float* __restrict__ whh1,
                       const float* __restrict__ w1, const float* __restrict__ wih0,
                       const float* __restrict__ wih1, const float* __restrict__ x,
                       const float* __restrict__ a,
                       unsigned int* __restrict__ whh0p, unsigned int* __restrict__ whh1p,
                       unsigned short* __restrict__ w1f, unsigned short* __restrict__ wi0f,
                       unsigned short* __restrict__ wi1f, unsigned short* __restrict__ xnf,
                       unsigned short* __restrict__ h1af){
  __shared__ __align__(4) unsigned short lt[12800];   // [k][c] stride 100
  int tid = threadIdx.x;
  int bx = blockIdx.x;
  if (bx < 128){
    int b = bx;
    unsigned int* l2 = (unsigned int*)lt;
    for (int e4 = tid; e4 < 3072; e4 += 256){
      int k = e4 / 24, c4 = (e4 - k*24)*4;
      const float4 v = *(const float4*)(Tm + k*(HID*CDIM) + b*CDIM + c4);
      int base = (k*100 + c4) >> 1;
      l2[base]   = (unsigned int)f2bf(v.x) | ((unsigned int)f2bf(v.y) << 16);
      l2[base+1] = (unsigned int)f2bf(v.z) | ((unsigned int)f2bf(v.w) << 16);
    }
    __syncthreads();
    unsigned int* tm2 = (unsigned int*)(tmh + b*(HID*CDIM));
    for (int e2 = tid; e2 < 6144; e2 += 256){
      int e = e2*2;
      int chunk = e / 768;
      int r1 = e - chunk*768;
      int c = r1 >> 3, h = r1 & 7;    // h even
      unsigned int lo = lt[(chunk*8 + h)*100 + c];
      unsigned int hi = lt[(chunk*8 + h + 1)*100 + c];
      tm2[e2] = lo | (hi << 16);
    }
  } else if (bx < 132){
    for (int e = (bx-128)*256 + tid; e < 24576; e += 1024){
      int k2 = e / 384, r = e - k2*384;
      whh0p[e] = packh2(whh0[r*128 + 2*k2], whh0[r*128 + 2*k2 + 1]);
      whh1p[e] = packh2(whh1[r*128 + 2*k2], whh1[r*128 + 2*k2 + 1]);
    }
  } else if (bx < 136){
    for (int e = (bx-132)*256 + tid; e < 20480; e += 1024){
      int kc = e >> 10, rem = e & 1023;
      int col = rem >> 3, j = rem & 7;
      w1f[e] = f2bf(w1[col*160 + kc*8 + j]);
    }
  } else if (bx < 140){
    for (int e = (bx-136)*256 + tid; e < 24576; e += 1024){
      int kc = e / 3072, rem = e - kc*3072;
      int col = rem >> 3, kl = rem & 7;
      wi0f[e] = f2bf(wih0[col*64 + kc*8 + kl]);
    }
  } else if (bx < 144){
    for (int e = (bx-140)*256 + tid; e < 49152; e += 1024){
      int kc = e / 3072, rem = e - kc*3072;
      int col = rem >> 3, kl = rem & 7;
      wi1f[e] = f2bf(wih1[col*128 + kc*8 + kl]);
    }
  } else if (bx < 156){
    for (int e = (bx-144)*256 + tid; e < 131072; e += 3072){
      int n = e >> 11, rem = e & 2047;
      int t = rem >> 6, k = rem & 63;
      xnf[e] = f2bf(x[t*4096 + n*64 + k]);
    }
  } else {
    for (int e = (bx-156)*256 + tid; e < 65536; e += 3072){
      int t = e >> 11, rem = e & 2047;
      int n = rem >> 5, c = rem & 31;
      int pos = t*10240 + (n>>4)*2560 + (16 + (c>>3))*128 + (n&15)*8 + (c&7);
      h1af[pos] = f2bf(a[t*(NB*ACT) + n*ACT + c]);
    }
  }
}

// ---------------- fused dual-layer GRU: gi0 prologue -> loop1 -> mid (gi1) -> loop2 ----------------
// gi0 = x_n @ wih0^T + bih0 computed per block via MFMA directly into gl (replaces
// the k_gi<2> launch + gig global roundtrip). Same frag pattern as the proven mid
// section, with K=64 (kk<2, A-row stride 8 uint4).
__global__ __launch_bounds__(768, 3) void k_rec2(const unsigned int* __restrict__ whh0p,
                                                 const unsigned int* __restrict__ whh1p,
                                                 const float* __restrict__ bhh0,
                                                 const float* __restrict__ bhh1,
                                                 const float* __restrict__ bih0,
                                                 const float* __restrict__ bih1,
                                                 const unsigned short* __restrict__ wi0f,
                                                 const unsigned short* __restrict__ wi1f,
                                                 const unsigned short* __restrict__ xnf,
                                                 unsigned short* __restrict__ h1af){
  __shared__ __align__(16) unsigned int hl[64];
  __shared__ float A0[G3];
  __shared__ __align__(16) float gl[T_STEPS*G3];               // 48 KB
  __shared__ __align__(16) unsigned short hist0[T_STEPS*136];  // h0 bf16, rows padded to 136
  __shared__ __align__(16) unsigned short hist1[T_STEPS*HID];  // 8 KB
  int n = blockIdx.x, tid = threadIdx.x;
  int r = tid >> 1, kh = tid & 1;
  // ---- prologue: gi0[t][col] = x_n @ wih0^T + bih0 via MFMA into gl ----
  {
    int wave = tid >> 6, lane = tid & 63, m = lane & 15, quad = lane >> 4;
    const uint4* B4 = (const uint4*)wi0f;
    const uint4* X4 = (const uint4*)(xnf + n*2048);   // 32 rows x 8 uint4
    f32x4 acc00 = (f32x4)(0.0f), acc01 = (f32x4)(0.0f);
    f32x4 acc10 = (f32x4)(0.0f), acc11 = (f32x4)(0.0f);
    int nt0 = wave*2;
    #pragma unroll
    for (int kk = 0; kk < 2; kk++){
      uint4 a0 = X4[m*8 + kk*4 + quad];          // t-tile 0: rows 0..15
      uint4 a1 = X4[(16 + m)*8 + kk*4 + quad];   // t-tile 1: rows 16..31
      uint4 b0 = B4[(kk*4 + quad)*384 + nt0*16 + m];
      uint4 b1 = B4[(kk*4 + quad)*384 + (nt0+1)*16 + m];
      short8 a0s = __builtin_bit_cast(short8, a0);
      short8 a1s = __builtin_bit_cast(short8, a1);
      short8 b0s = __builtin_bit_cast(short8, b0);
      short8 b1s = __builtin_bit_cast(short8, b1);
      acc00 = __builtin_amdgcn_mfma_f32_16x16x32_bf16(a0s, b0s, acc00, 0, 0, 0);
      acc01 = __builtin_amdgcn_mfma_f32_16x16x32_bf16(a0s, b1s, acc01, 0, 0, 0);
      acc10 = __builtin_amdgcn_mfma_f32_16x16x32_bf16(a1s, b0s, acc10, 0, 0, 0);
      acc11 = __builtin_amdgcn_mfma_f32_16x16x32_bf16(a1s, b1s, acc11, 0, 0, 0);
    }
    float bv0 = bih0[nt0*16 + m];
    float bv1 = bih0[(nt0+1)*16 + m];
    #pragma unroll
    for (int rr = 0; rr < 4; rr++){
      gl[(quad*4 + rr)*G3 + nt0*16 + m]          = acc00[rr] + bv0;
      gl[(quad*4 + rr)*G3 + (nt0+1)*16 + m]      = acc01[rr] + bv1;
      gl[(16 + quad*4 + rr)*G3 + nt0*16 + m]     = acc10[rr] + bv0;
      gl[(16 + quad*4 + rr)*G3 + (nt0+1)*16 + m] = acc11[rr] + bv1;
    }
  }
  unsigned int wh[32];
  #pragma unroll
  for (int i = 0; i < 32; i++) wh[i] = whh0p[(kh*32 + i)*384 + r];
  float bh = (kh == 0) ? bhh0[r] : 0.0f;
  if (tid < 64) hl[tid] = 0u;
  float hprev = 0.0f;
  __syncthreads();
  const uint4* h4 = (const uint4*)hl;
  // ---- loop 1: layer-0 recurrence ----
  for (int t = 0; t < T_STEPS; t++){
    float s0 = 0.0f, s1 = 0.0f, s2 = 0.0f, s3 = 0.0f;
    #pragma unroll
    for (int g = 0; g < 2; g++){
      uint4 hv[4];
      #pragma unroll
      for (int j = 0; j < 4; j++) hv[j] = h4[kh*8 + g*4 + j];
      s0 = dot2f(s0, wh[g*16 + 0], hv[0].x);  s0 = dot2f(s0, wh[g*16 + 1], hv[0].y);
      s0 = dot2f(s0, wh[g*16 + 2], hv[0].z);  s0 = dot2f(s0, wh[g*16 + 3], hv[0].w);
      s1 = dot2f(s1, wh[g*16 + 4], hv[1].x);  s1 = dot2f(s1, wh[g*16 + 5], hv[1].y);
      s1 = dot2f(s1, wh[g*16 + 6], hv[1].z);  s1 = dot2f(s1, wh[g*16 + 7], hv[1].w);
      s2 = dot2f(s2, wh[g*16 + 8], hv[2].x);  s2 = dot2f(s2, wh[g*16 + 9], hv[2].y);
      s2 = dot2f(s2, wh[g*16 +10], hv[2].z);  s2 = dot2f(s2, wh[g*16 +11], hv[2].w);
      s3 = dot2f(s3, wh[g*16 +12], hv[3].x);  s3 = dot2f(s3, wh[g*16 +13], hv[3].y);
      s3 = dot2f(s3, wh[g*16 +14], hv[3].z);  s3 = dot2f(s3, wh[g*16 +15], hv[3].w);
    }
    float gh = bh + ((s0 + s1) + (s2 + s3));
    gh += __shfl_xor(gh, 1);
    if (kh == 0) A0[r] = gh;
    __syncthreads();
    if (tid < HID){
      const float* gp = gl + t*G3;
      float rg = sigmoidf_(gp[tid]       + A0[tid]);
      float z  = sigmoidf_(gp[tid+HID]   + A0[tid+HID]);
      float nn = tanhf_   (gp[tid+2*HID] + rg*A0[tid+2*HID]);
      float hn = (1.0f - z)*nn + z*hprev;
      hprev = hn;
      ((__half*)hl)[tid] = __float2half_rn(hn);
      hist0[t*136 + tid] = f2bf(hn);
    }
    __syncthreads();
  }
  // ---- mid: gi1[t][col] = h0 @ wih1^T + bih1 via MFMA, written into gl ----
  {
    int wave = tid >> 6, lane = tid & 63, m = lane & 15, quad = lane >> 4;
    const uint4* B4 = (const uint4*)wi1f;
    const uint4* H4 = (const uint4*)hist0;   // row stride 17 uint4 (136 ushorts)
    f32x4 acc00 = (f32x4)(0.0f), acc01 = (f32x4)(0.0f);
    f32x4 acc10 = (f32x4)(0.0f), acc11 = (f32x4)(0.0f);
    int nt0 = wave*2;
    #pragma unroll
    for (int kk = 0; kk < 4; kk++){
      uint4 a0 = H4[m*17 + kk*4 + quad];          // t-tile 0: rows 0..15
      uint4 a1 = H4[(16 + m)*17 + kk*4 + quad];   // t-tile 1: rows 16..31
      uint4 b0 = B4[(kk*4 + quad)*384 + nt0*16 + m];
      uint4 b1 = B4[(kk*4 + quad)*384 + (nt0+1)*16 + m];
      short8 a0s = __builtin_bit_cast(short8, a0);
      short8 a1s = __builtin_bit_cast(short8, a1);
      short8 b0s = __builtin_bit_cast(short8, b0);
      short8 b1s = __builtin_bit_cast(short8, b1);
      acc00 = __builtin_amdgcn_mfma_f32_16x16x32_bf16(a0s, b0s, acc00, 0, 0, 0);
      acc01 = __builtin_amdgcn_mfma_f32_16x16x32_bf16(a0s, b1s, acc01, 0, 0, 0);
      acc10 = __builtin_amdgcn_mfma_f32_16x16x32_bf16(a1s, b0s, acc10, 0, 0, 0);
      acc11 = __builtin_amdgcn_mfma_f32_16x16x32_bf16(a1s, b1s, acc11, 0, 0, 0);
    }
    float bv0 = bih1[nt0*16 + m];
    float bv1 = bih1[(nt0+1)*16 + m];
    #pragma unroll
    for (int rr = 0; rr < 4; rr++){
      gl[(quad*4 + rr)*G3 + nt0*16 + m]        = acc00[rr] + bv0;
      gl[(quad*4 + rr)*G3 + (nt0+1)*16 + m]    = acc01[rr] + bv1;
      gl[(16 + quad*4 + rr)*G3 + nt0*16 + m]   = acc10[rr] + bv0;
      gl[(16 + quad*4 + rr)*G3 + (nt0+1)*16 + m] = acc11[rr] + bv1;
    }
  }
  // ---- reload weights for layer 1 (reuse wh[]) ----
  asm volatile("" ::: "memory");
  #pragma unroll
  for (int i = 0; i < 32; i++) wh[i] = whh1p[(kh*32 + i)*384 + r];
  bh = (kh == 0) ? bhh1[r] : 0.0f;
  if (tid < 64) hl[tid] = 0u;
  hprev = 0.0f;
  __syncthreads();
  // ---- loop 2: layer-1 recurrence (gl holds gi1 incl. bias) ----
  for (int t = 0; t < T_STEPS; t++){
    float s0 = 0.0f, s1 = 0.0f, s2 = 0.0f, s3 = 0.0f;
    #pragma unroll
    for (int g = 0; g < 2; g++){
      uint4 hv[4];
      #pragma unroll
      for (int j = 0; j < 4; j++) hv[j] = h4[kh*8 + g*4 + j];
      s0 = dot2f(s0, wh[g*16 + 0], hv[0].x);  s0 = dot2f(s0, wh[g*16 + 1], hv[0].y);
      s0 = dot2f(s0, wh[g*16 + 2], hv[0].z);  s0 = dot2f(s0, wh[g*16 + 3], hv[0].w);
      s1 = dot2f(s1, wh[g*16 + 4], hv[1].x);  s1 = dot2f(s1, wh[g*16 + 5], hv[1].y);
      s1 = dot2f(s1, wh[g*16 + 6], hv[1].z);  s1 = dot2f(s1, wh[g*16 + 7], hv[1].w);
      s2 = dot2f(s2, wh[g*16 + 8], hv[2].x);  s2 = dot2f(s2, wh[g*16 + 9], hv[2].y);
      s2 = dot2f(s2, wh[g*16 +10], hv[2].z);  s2 = dot2f(s2, wh[g*16 +11], hv[2].w);
      s3 = dot2f(s3, wh[g*16 +12], hv[3].x);  s3 = dot2f(s3, wh[g*16 +13], hv[3].y);
      s3 = dot2f(s3, wh[g*16 +14], hv[3].z);  s3 = dot2f(s3, wh[g*16 +15], hv[3].w);
    }
    float gh = bh + ((s0 + s1) + (s2 + s3));
    gh += __shfl_xor(gh, 1);
    if (kh == 0) A0[r] = gh;
    __syncthreads();
    if (tid < HID){
      const float* gp = gl + t*G3;
      float rg = sigmoidf_(gp[tid]       + A0[tid]);
      float z  = sigmoidf_(gp[tid+HID]   + A0[tid+HID]);
      float nn = tanhf_   (gp[tid+2*HID] + rg*A0[tid+2*HID]);
      float hn = (1.0f - z)*nn + z*hprev;
      hprev = hn;
      ((__half*)hl)[tid] = __float2half_rn(hn);
      hist1[t*HID + tid] = f2bf(hn);
    }
    __syncthreads();
  }
  // flush h1 history (uint4 = 8 bf16), layout matches fc1's A-frags
  if (tid < T_STEPS*16){
    int t = tid >> 4, j = tid & 15;
    uint4 v = *(const uint4*)(hist1 + t*HID + j*8);
    *(uint4*)(h1af + t*10240 + (n>>4)*2560 + j*128 + (n&15)*8) = v;
  }
}

// ---------------- fc1 ----------------
__global__ __launch_bounds__(256) void k_fc1(const unsigned short* __restrict__ h1af,
                                             const unsigned short* __restrict__ w1f,
                                             const float* __restrict__ b1,
                                             unsigned short* __restrict__ fc1h){
  __shared__ float b1s[128];
  int t = blockIdx.x, tid = threadIdx.x;
  int wave = tid >> 6, lane = tid & 63, m = lane & 15, quad = lane >> 4;
  if (tid < 128) b1s[tid] = b1[tid];
  const uint4* A4 = (const uint4*)(h1af + t*10240);
  const uint4* B4 = (const uint4*)w1f;
  f32x4 acc[8];
  #pragma unroll
  for (int i = 0; i < 8; i++) acc[i] = (f32x4)(0.0f);
  #pragma unroll
  for (int ks = 0; ks < 5; ks++){
    uint4 av = A4[wave*320 + (ks*4 + quad)*16 + m];
    short8 avs = __builtin_bit_cast(short8, av);
    #pragma unroll
    for (int nt = 0; nt < 8; nt++){
      uint4 bv = B4[(ks*4 + quad)*128 + nt*16 + m];
      acc[nt] = __builtin_amdgcn_mfma_f32_16x16x32_bf16(avs, __builtin_bit_cast(short8, bv), acc[nt], 0, 0, 0);
    }
  }
  __syncthreads();
  #pragma unroll
  for (int nt = 0; nt < 8; nt++){
    float bj = b1s[nt*16 + m];
    #pragma unroll
    for (int rr = 0; rr < 4; rr++){
      float v = fmaxf(acc[nt][rr] + bj, 0.0f);
      fc1h[t*8192 + wave*2048 + (nt*2 + (m>>3))*128 + (quad*4 + rr)*8 + (m&7)] = f2bf(v);
    }
  }
}

// ---------------- minibatch discrimination: one block per (b, t) (round-5 proven) ----------------
__global__ __launch_bounds__(256) void k_disc(const unsigned short* __restrict__ fc1h,
                                              const unsigned short* __restrict__ tmh,
                                              float* __restrict__ O){
  __shared__ __align__(16) __half Mh[64*120];     // cols 0..95 = M, 96..103 = S8
  __shared__ unsigned short plist[2016];
  __shared__ float osum[64];
  __shared__ unsigned int cnt;
  int b = blockIdx.x, t = blockIdx.y;
  int tid = threadIdx.x;
  int wave = tid >> 6, lane = tid & 63, m = lane & 15, quad = lane >> 4;
  if (tid < 64) osum[tid] = 0.0f;
  if (tid == 0) cnt = 0u;
  const uint4* Bg = (const uint4*)(tmh + b*(CDIM*HID));
  const uint4* Ag = (const uint4*)(fc1h + t*8192);
  uint4 a4[4];
  #pragma unroll
  for (int kk = 0; kk < 4; kk++) a4[kk] = Ag[wave*256 + (kk*4 + quad)*16 + m];
  f32x4 acc[6];
  #pragma unroll
  for (int i = 0; i < 6; i++) acc[i] = (f32x4)(0.0f);
  #pragma unroll
  for (int kk = 0; kk < 4; kk++){
    short8 av = __builtin_bit_cast(short8, a4[kk]);
    #pragma unroll
    for (int nt = 0; nt < 6; nt++){
      uint4 b4 = Bg[(kk*4 + quad)*96 + nt*16 + m];
      acc[nt] = __builtin_amdgcn_mfma_f32_16x16x32_bf16(av, __builtin_bit_cast(short8, b4), acc[nt], 0, 0, 0);
    }
  }
  #pragma unroll
  for (int nt = 0; nt < 6; nt++){
    #pragma unroll
    for (int rr = 0; rr < 4; rr++){
      Mh[(wave*16 + quad*4 + rr)*120 + nt*16 + m] = __float2half(acc[nt][rr]);
    }
  }
  __syncthreads();
  const unsigned int ONES2 = 0x3C003C00u;  // (1.0h, 1.0h)
  #pragma unroll
  for (int idx = tid; idx < 512; idx += 256){
    int r = idx >> 3, jc = idx & 7;
    const unsigned int* row = (const unsigned int*)(Mh + r*120 + jc*12);
    float s = 0.0f;
    #pragma unroll
    for (int q = 0; q < 6; q++) s = dot2f(s, row[q], ONES2);
    Mh[r*120 + 96 + jc] = __float2half(s);
  }
  __syncthreads();
  const uint4* M4 = (const uint4*)Mh;
  for (int p = tid; p < 2016; p += 256){
    int r = p >> 5, s = p & 31;
    int i, j;
    if (s == 0){ i = 63; j = r; }
    else {
      i = r + s;      if (i >= 63) i -= 63;
      j = r + 63 - s; if (j >= 63) j -= 63;
    }
    uint4 qa = M4[i*15 + 12];
    uint4 qb = M4[j*15 + 12];
    float lb = l1d4(0.0f, qa, qb);
    if (lb <= 14.5f){
      unsigned int k = atomicAdd(&cnt, 1u);
      plist[k] = (unsigned short)(i*64 + j);
    }
  }
  __syncthreads();
  int ns = (int)cnt;
  if (ns > 2016) ns = 2016;
  for (int v = tid; v < ns; v += 256){
    int pr = plist[v];
    int i = pr >> 6, j = pr & 63;
    float L = 0.0f;
    #pragma unroll
    for (int c = 0; c < 12; c++){
      L = l1d4(L, M4[i*15 + c], M4[j*15 + c]);
    }
    float e = __expf(-L);
    atomicAdd(&osum[i], e);
    atomicAdd(&osum[j], e);
  }
  __syncthreads();
  if (tid < 64) O[(t*HID + b)*NB + tid] = osum[tid]*(1.0f/63.0f);
}

// ---------------- final: 4-wave parallel dot ----------------
__global__ __launch_bounds__(256) void k_final(const unsigned short* __restrict__ fc1h,
                                               const float* __restrict__ O,
                                               const float* __restrict__ w2, const float* __restrict__ b2,
                                               float* __restrict__ out){
  __shared__ float ol[NB*HID];
  __shared__ unsigned short fr[8192];
  __shared__ float wl[2*HID + 2];
  __shared__ float pp[4][NB];
  int t = blockIdx.x, tid = threadIdx.x;
  for (int i = tid; i < NB*HID; i += 256) ol[i] = O[t*NB*HID + i];
  const uint4* Fg = (const uint4*)(fc1h + t*8192);
  for (int i = tid; i < 1024; i += 256) ((uint4*)fr)[i] = Fg[i];
  if (tid < 2*HID) wl[tid] = w2[tid];
  if (tid == 0) wl[2*HID] = b2[0];
  __syncthreads();
  int n = tid & 63, part = tid >> 6;
  float acc = 0.0f;
  int base = (n>>4)*2048 + (n&15)*8;
  #pragma unroll
  for (int jc = 0; jc < 4; jc++){
    int j8 = part*4 + jc;
    #pragma unroll
    for (int k = 0; k < 8; k++)
      acc += bf2f(fr[base + j8*128 + k])*wl[j8*8 + k];
  }
  #pragma unroll 8
  for (int bb = 0; bb < 32; bb++){
    int bq = part*32 + bb;
    acc += ol[bq*NB + n]*wl[HID + bq];
  }
  pp[part][n] = acc;
  __syncthreads();
  if (tid < NB){
    float s = wl[2*HID] + pp[0][tid] + pp[1][tid] + pp[2][tid] + pp[3][tid];
    out[t*NB + tid] = sigmoidf_(s);
  }
}

extern "C" void kernel_launch(void* const* d_in, const int* in_sizes, int n_in,
                              void* d_out, int out_size, void* d_ws, size_t ws_size,
                              hipStream_t stream){
  const float* x    = (const float*)d_in[0];
  const float* a    = (const float*)d_in[1];
  const float* wih0 = (const float*)d_in[2];
  const float* whh0 = (const float*)d_in[3];
  const float* bih0 = (const float*)d_in[4];
  const float* bhh0 = (const float*)d_in[5];
  const float* wih1 = (const float*)d_in[6];
  const float* whh1 = (const float*)d_in[7];
  const float* bih1 = (const float*)d_in[8];
  const float* bhh1 = (const float*)d_in[9];
  const float* w1   = (const float*)d_in[10];
  const float* b1   = (const float*)d_in[11];
  const float* w2   = (const float*)d_in[12];
  const float* b2   = (const float*)d_in[13];
  const float* Tm   = (const float*)d_in[14];
  float* ws = (float*)d_ws;
  float* Ows = ws;                                          // 262144 floats
  unsigned int* whh0p = (unsigned int*)(ws + 262144);       // 24576 dwords
  unsigned int* whh1p = (unsigned int*)(ws + 286720);       // 24576
  unsigned short* tmh  = (unsigned short*)(ws + 311296);    // 1572864 ushorts
  unsigned short* fc1h = (unsigned short*)(ws + 1097728);   // 262144 ushorts
  unsigned short* h1af = (unsigned short*)(ws + 1228800);   // 327680 ushorts
  unsigned short* w1f  = (unsigned short*)(ws + 1392640);   // 20480 ushorts
  unsigned short* xnf  = (unsigned short*)(ws + 1402880);   // 131072 ushorts
  unsigned short* wi0f = (unsigned short*)(ws + 1468416);   // 24576 ushorts
  unsigned short* wi1f = (unsigned short*)(ws + 1480704);   // 49152 ushorts
  float* out = (float*)d_out;

  k_prep<<<dim3(168), dim3(256), 0, stream>>>(Tm, tmh, whh0, whh1, w1, wih0, wih1, x, a,
                                              whh0p, whh1p, w1f, wi0f, wi1f, xnf, h1af);
  k_rec2<<<dim3(NB), dim3(768), 0, stream>>>(whh0p, whh1p, bhh0, bhh1, bih0, bih1,
                                             wi0f, wi1f, xnf, h1af);
  k_fc1<<<dim3(T_STEPS), dim3(256), 0, stream>>>(h1af, w1f, b1, fc1h);
  k_disc<<<dim3(HID, T_STEPS), dim3(256), 0, stream>>>(fc1h, tmh, Ows);
  k_final<<<dim3(T_STEPS), dim3(256), 0, stream>>>(fc1h, Ows, w2, b2, out);
}